// Round 4
// baseline (2252.448 us; speedup 1.0000x reference)
//
#include <hip/hip_runtime.h>

namespace {
constexpr int NB = 1024, NT = 1024, NH = 128;
constexpr float L2E = 1.4426950408889634f;

typedef __bf16 bf16x8 __attribute__((ext_vector_type(8)));
typedef float  f32x4  __attribute__((ext_vector_type(4)));
typedef int    i32x4  __attribute__((ext_vector_type(4)));
union FRAG { i32x4 i; bf16x8 b; };

__device__ __forceinline__ unsigned short bfb(float f) {   // HW RNE f32->bf16
  union { __bf16 h; unsigned short u; } c; c.h = (__bf16)f; return c.u;
}
__device__ __forceinline__ float ex2(float x) { return __builtin_amdgcn_exp2f(x); }
__device__ __forceinline__ float rcp_(float x) { return __builtin_amdgcn_rcpf(x); }

// 8 consecutive floats -> bf16 B-fragment (k = 32s + 8lg + j, round-1 verified map)
__device__ __forceinline__ FRAG pk8(const float* pp, float sc) {
  FRAG f;
  #pragma unroll
  for (int j = 0; j < 4; ++j)
    f.i[j] = (int)((unsigned)bfb(pp[2 * j] * sc) |
                   ((unsigned)bfb(pp[2 * j + 1] * sc) << 16));
  return f;
}
} // namespace

#define MFMA(a, b, c) __builtin_amdgcn_mfma_f32_16x16x32_bf16(a, b, c, 0, 0, 0)

// One block = 16 batch rows, 1024 threads (16 waves).
// Waves 0-7  (gate): GRU-D recurrence for step t   (verified round-1 data paths)
// Waves 8-15 (head): head-L1 for step t-1, head-L2 for step t-2 (pipelined),
//                    plus x_hat lanes (waves 8-11) and x stagers (waves 12-15).
// ONE __syncthreads per iteration; all LDS buffers double-buffered by parity.
__global__ __launch_bounds__(1024)
void grud_fused(const float* __restrict__ x,   const float* __restrict__ x_mean,
                const float* __restrict__ dxw, const float* __restrict__ dxb,
                const float* __restrict__ dhw, const float* __restrict__ dhb,
                const float* __restrict__ w_ih, const float* __restrict__ w_hh,
                const float* __restrict__ b_ih, const float* __restrict__ b_hh,
                const float* __restrict__ w1,  const float* __restrict__ b1,
                const float* __restrict__ w2,  const float* __restrict__ b2,
                const float* __restrict__ wu1, const float* __restrict__ bu1,
                const float* __restrict__ wu2, const float* __restrict__ bu2,
                float* __restrict__ out)
{
  __shared__ __align__(16) float          xw[2][16][16];   // x rows (13 used)
  __shared__ __align__(16) unsigned short gin[2][16][32];  // interleaved x̂/m + bias col
  __shared__ __align__(16) unsigned short hdb[2][2048];    // decayed h, swizzled
  __shared__ __align__(16) unsigned short hnb[2][2048];    // new h, swizzled
  __shared__ __align__(16) unsigned short y1b[2][2048];    // relu(h@w1+b1)
  __shared__ __align__(16) unsigned short u1b[2][1024];    // relu(h@wu1+bu1)

  const int tid = threadIdx.x, lane = tid & 63, wv = tid >> 6;
  const int lr = lane & 15, lg = lane >> 4;
  const int b0 = blockIdx.x * 16;
  const bool isGate = wv < 8;
  const int hw = wv & 7;

  // ---------------- role-shared weight fragment storage ----------------
  FRAG wf[15];
  float bhnS = 0.f, dhwS = 0.f, dhbS = 0.f;                 // gate scalars
  float b1l = 0.f, bu1l = 0.f, b2l = 0.f, bu2l = 0.f;       // head scalars

  if (isGate) {
    const int uidx = wv * 16 + lr;
    #pragma unroll
    for (int g = 0; g < 3; ++g) {
      const float sc = (g < 2) ? -L2E : 2.f * L2E;
      const int grow = g * 128 + uidx;
      const float* wrow = w_hh + (size_t)grow * NH;
      #pragma unroll
      for (int s = 0; s < 4; ++s) wf[g * 4 + s] = pk8(wrow + 32 * s + 8 * lg, sc);
      FRAG f; f.i = i32x4{0, 0, 0, 0};
      if (lg < 2) {
        unsigned e[8];
        #pragma unroll
        for (int j = 0; j < 8; ++j) {
          const int c = 8 * lg + j; float v = 0.f;
          if (c < 12) {
            const int ch = c >> 1;
            v = ((c & 1) ? w_ih[(size_t)grow * 12 + 6 + ch]
                         : w_ih[(size_t)grow * 12 + ch]) * sc;
          } else if (c == 12) {
            v = ((g < 2) ? (b_ih[grow] + b_hh[grow]) : b_ih[grow]) * sc;
          }
          e[j] = bfb(v);
        }
        f.i[0] = (int)(e[0] | (e[1] << 16)); f.i[1] = (int)(e[2] | (e[3] << 16));
        f.i[2] = (int)(e[4] | (e[5] << 16)); f.i[3] = (int)(e[6] | (e[7] << 16));
      }
      wf[12 + g] = f;
    }
    bhnS = b_hh[256 + uidx] * (2.f * L2E);
    dhwS = -L2E * dhw[uidx]; dhbS = -L2E * dhb[uidx];
  } else {
    #pragma unroll
    for (int s = 0; s < 4; ++s) {
      wf[s]     = pk8(w1  + (size_t)(hw * 16 + lr) * 128 + 32 * s + 8 * lg, 1.f);
      wf[4 + s] = pk8(wu1 + (size_t)((hw & 3) * 16 + lr) * 128 + 32 * s + 8 * lg, 1.f);
      if (lr < 6) wf[8 + s] = pk8(w2 + (size_t)lr * 128 + 32 * s + 8 * lg, 1.f);
      else        wf[8 + s].i = i32x4{0, 0, 0, 0};
    }
    #pragma unroll
    for (int s = 0; s < 2; ++s) {
      if (lr < 6) wf[12 + s] = pk8(wu2 + (size_t)lr * 64 + 32 * s + 8 * lg, 1.f);
      else        wf[12 + s].i = i32x4{0, 0, 0, 0};
    }
    wf[14].i = i32x4{0, 0, 0, 0};
    b1l = b1[hw * 16 + lr]; bu1l = bu1[(hw & 3) * 16 + lr];
    b2l = (lr < 6) ? b2[lr] : 0.f; bu2l = (lr < 6) ? bu2[lr] : 0.f;
  }

  // ---------------- constant per-lane LDS offsets (u16 indices) ----------------
  int rdo[4];                    // A-frag reads, row = lr (hdb/hnb/y1b pattern)
  #pragma unroll
  for (int s = 0; s < 4; ++s) rdo[s] = lr * 128 + (((s * 4 + lg) ^ (lr & 7)) << 3);
  int rdo64[2];                  // u1b reads (K=64)
  #pragma unroll
  for (int s = 0; s < 2; ++s) rdo64[s] = lr * 64 + (((s * 4 + lg) ^ (lr & 7)) << 3);
  int wro[4], w1o[4], u1o[4];    // writes: gate h (col=uidx), head y1/u1 (col=cy/cu)
  {
    const int uidx = wv * 16 + lr;
    const int cy = hw * 16 + lr, cu = (hw & 3) * 16 + lr;
    #pragma unroll
    for (int r = 0; r < 4; ++r) {
      const int m = 4 * lg + r;
      wro[r] = m * 128 + (((uidx >> 3) ^ (m & 7)) << 3) + (lr & 7);
      w1o[r] = m * 128 + (((cy >> 3) ^ (m & 7)) << 3) + (cy & 7);
      u1o[r] = m * 64  + (((cu >> 3) ^ (m & 7)) << 3) + (cu & 7);
    }
  }

  // ---------------- x̂ lanes (waves 8-11, lanes 0-23) ----------------
  const bool xl = (!isGate) && (wv < 12) && (lane < 24);
  const int xi = (wv - 8) * 24 + lane;
  int xrow = 0, xch = 0;
  float dxwS = 0.f, dxbS = 0.f, xm_l = 0.f, run = 0.f, xlast = 0.f;
  if (xl) {
    xrow = xi / 6; xch = xi - 6 * xrow;
    dxwS = -L2E * dxw[xch]; dxbS = -L2E * dxb[xch]; xm_l = x_mean[xch];
  }

  // ---------------- stagers (waves 12-15, sid<208) ----------------
  const int sid = tid - 768;
  const bool sl = (sid >= 0) && (sid < 208);
  int rrow = 0, rcc = 0;
  if (sl) { rrow = sid / 13; rcc = sid - 13 * rrow; }
  const float* xbase = x + (size_t)(b0 + rrow) * (NT * 13) + rcc;

  // ---------------- prologue ----------------
  if (tid < 640) {   // gin cols 12..31 (bias col = 1.0, rest 0), both buffers
    const int buf = tid / 320, rem = tid - 320 * buf;
    const int row = rem / 20, c = 12 + rem - 20 * (rem / 20);
    gin[buf][row][c] = (c == 12) ? (unsigned short)0x3F80 : (unsigned short)0;
  }
  ((unsigned*)hdb)[tid] = 0u;    // hdb[0] = 0  (h starts at 0)
  if (sl) { xw[0][rrow][rcc] = xbase[0]; xw[1][rrow][rcc] = xbase[13]; }
  __syncthreads();
  float xr2 = 0.f;
  if (xl) {                      // x̂ for t = 0
    const float xv = xw[0][xrow][xch], mt = xw[0][xrow][6 + xch];
    const float dtv = xw[0][xrow][12];
    const bool obs = mt > 0.5f;
    run = obs ? 0.f : run + dtv;
    const float gx = ex2(fminf(run * dxwS + dxbS, 0.f));
    xlast = obs ? xv : xlast;
    const float xh = mt * xv + (1.f - mt) * (gx * xlast + (1.f - gx) * xm_l);
    ((unsigned*)&gin[0][xrow][0])[xch] = (unsigned)bfb(xh) | ((unsigned)bfb(mt) << 16);
  }
  if (sl) xr2 = xbase[26];       // x[2]
  __syncthreads();

  f32x4 hd = {0.f, 0.f, 0.f, 0.f}, hn = {0.f, 0.f, 0.f, 0.f};
  const f32x4 z4 = {0.f, 0.f, 0.f, 0.f};

  // ---------------- main loop: gates(t) | L1(t-1) | L2(t-2) ----------------
  #pragma unroll 1
  for (int t = 0; t < NT + 2; ++t) {
    const int p = t & 1, q = p ^ 1;
    if (isGate) {
      if (t < NT) {
        const unsigned short* hdbP = hdb[p];
        FRAG ag; ag.i = *(const i32x4*)&gin[p][lr][8 * lg];
        f32x4 accr = MFMA(ag.b, wf[12].b, z4);
        f32x4 accz = MFMA(ag.b, wf[13].b, z4);
        f32x4 ani  = MFMA(ag.b, wf[14].b, z4);
        f32x4 anh  = z4;
        #pragma unroll
        for (int s = 0; s < 4; ++s) {
          FRAG ah; ah.i = *(const i32x4*)&hdbP[rdo[s]];
          accr = MFMA(ah.b, wf[s].b, accr);
          accz = MFMA(ah.b, wf[4 + s].b, accz);
          anh  = MFMA(ah.b, wf[8 + s].b, anh);
        }
        f32x4 dtn;
        #pragma unroll
        for (int r = 0; r < 4; ++r) dtn[r] = xw[q][4 * lg + r][12];
        #pragma unroll
        for (int r = 0; r < 4; ++r) {
          const float rr = rcp_(1.f + ex2(accr[r]));
          const float na = ani[r] + rr * (anh[r] + bhnS);
          const float nn = 1.f - 2.f * rcp_(1.f + ex2(na));
          const float zz = rcp_(1.f + ex2(accz[r]));
          hn[r] = nn + zz * (hd[r] - nn);
        }
        unsigned short* hnbP = hnb[p];
        unsigned short* hdbN = hdb[q];
        #pragma unroll
        for (int r = 0; r < 4; ++r) {
          hnbP[wro[r]] = bfb(hn[r]);
          const float g2 = ex2(fminf(dtn[r] * dhwS + dhbS, 0.f));
          hd[r] = g2 * hn[r];
          hdbN[wro[r]] = bfb(hd[r]);
        }
      }
    } else {
      if (t >= 1 && t <= NT) {           // L1 for step t-1 (parity q)
        const unsigned short* hnbP = hnb[q];
        FRAG ahh[4];
        #pragma unroll
        for (int s = 0; s < 4; ++s) ahh[s].i = *(const i32x4*)&hnbP[rdo[s]];
        f32x4 a1 = z4;
        #pragma unroll
        for (int s = 0; s < 4; ++s) a1 = MFMA(ahh[s].b, wf[s].b, a1);
        unsigned short* y1P = y1b[q];
        #pragma unroll
        for (int r = 0; r < 4; ++r) y1P[w1o[r]] = bfb(fmaxf(a1[r] + b1l, 0.f));
        if (hw < 4) {
          f32x4 au = z4;
          #pragma unroll
          for (int s = 0; s < 4; ++s) au = MFMA(ahh[s].b, wf[4 + s].b, au);
          unsigned short* u1P = u1b[q];
          #pragma unroll
          for (int r = 0; r < 4; ++r) u1P[u1o[r]] = bfb(fmaxf(au[r] + bu1l, 0.f));
        }
      }
      if (t >= 2) {                      // L2 for step t-2 (parity p)
        const int s2 = t - 2;
        if (wv == 14) {
          const unsigned short* yP = y1b[p];
          f32x4 ap = z4;
          #pragma unroll
          for (int s = 0; s < 4; ++s) {
            FRAG ay; ay.i = *(const i32x4*)&yP[rdo[s]];
            ap = MFMA(ay.b, wf[8 + s].b, ap);
          }
          if (lr < 6) {
            #pragma unroll
            for (int r = 0; r < 4; ++r)
              out[((size_t)(b0 + 4 * lg + r) * NT + s2) * 6 + lr] = ap[r] + b2l;
          }
        } else if (wv == 15) {
          const unsigned short* uP = u1b[p];
          f32x4 aq = z4;
          #pragma unroll
          for (int s = 0; s < 2; ++s) {
            FRAG ay; ay.i = *(const i32x4*)&uP[rdo64[s]];
            aq = MFMA(ay.b, wf[12 + s].b, aq);
          }
          if (lr < 6) {
            #pragma unroll
            for (int r = 0; r < 4; ++r) {
              const float xa = aq[r] + bu2l;
              const float sp = fmaxf(xa, 0.f) + 0.6931471805599453f *
                  __builtin_amdgcn_logf(1.f + ex2(-fabsf(xa) * L2E));
              out[(size_t)NB * NT * 6 +
                  ((size_t)(b0 + 4 * lg + r) * NT + s2) * 6 + lr] = sp;
            }
          }
        }
      }
      if (xl && t + 1 < NT) {            // x̂ for step t+1 (reads xw[q] -> gin[q])
        const float xv = xw[q][xrow][xch], mt = xw[q][xrow][6 + xch];
        const float dtv = xw[q][xrow][12];
        const bool obs = mt > 0.5f;
        run = obs ? 0.f : run + dtv;
        const float gx = ex2(fminf(run * dxwS + dxbS, 0.f));
        xlast = obs ? xv : xlast;
        const float xh = mt * xv + (1.f - mt) * (gx * xlast + (1.f - gx) * xm_l);
        ((unsigned*)&gin[q][xrow][0])[xch] = (unsigned)bfb(xh) | ((unsigned)bfb(mt) << 16);
      }
      if (sl && t + 2 < NT) {            // stage x[t+2] -> xw[p]; prefetch x[t+3]
        xw[p][rrow][rcc] = xr2;
        xr2 = xbase[(size_t)((t + 3 < NT) ? t + 3 : NT - 1) * 13];
      }
    }
    __syncthreads();
  }
}

extern "C" void kernel_launch(void* const* d_in, const int* in_sizes, int n_in,
                              void* d_out, int out_size, void* d_ws, size_t ws_size,
                              hipStream_t stream) {
  (void)in_sizes; (void)n_in; (void)out_size; (void)d_ws; (void)ws_size;
  const float* p[18];
  for (int i = 0; i < 18; ++i) p[i] = (const float*)d_in[i];
  hipLaunchKernelGGL(grud_fused, dim3(64), dim3(1024), 0, stream,
                     p[0], p[1], p[2], p[3], p[4], p[5], p[6], p[7], p[8], p[9],
                     p[10], p[11], p[12], p[13], p[14], p[15], p[16], p[17],
                     (float*)d_out);
}

// Round 5
// 1083.303 us; speedup vs baseline: 2.0792x; 2.0792x over previous
//
#include <hip/hip_runtime.h>

namespace {
constexpr int NB = 1024, NT = 1024, NH = 128;
constexpr float L2E = 1.4426950408889634f;

typedef __bf16 bf16x8 __attribute__((ext_vector_type(8)));
typedef float  f32x4  __attribute__((ext_vector_type(4)));
typedef int    i32x4  __attribute__((ext_vector_type(4)));
union FRAG { i32x4 i; bf16x8 b; };

__device__ __forceinline__ unsigned short bfb(float f) {   // HW RNE f32->bf16
  union { __bf16 h; unsigned short u; } c; c.h = (__bf16)f; return c.u;
}
__device__ __forceinline__ unsigned pkbf(float a, float b) {
  return (unsigned)bfb(a) | ((unsigned)bfb(b) << 16);
}
__device__ __forceinline__ unsigned long long pk4(const f32x4 v) {
  return (unsigned long long)pkbf(v[0], v[1]) |
         ((unsigned long long)pkbf(v[2], v[3]) << 32);
}
__device__ __forceinline__ float ex2(float x) { return __builtin_amdgcn_exp2f(x); }
__device__ __forceinline__ float rcp_(float x) { return __builtin_amdgcn_rcpf(x); }

// 8 consecutive floats -> bf16 fragment (k = 32s + 8lg + j map, verified r0/r1)
__device__ __forceinline__ FRAG pk8(const float* pp, float sc) {
  FRAG f;
  #pragma unroll
  for (int j = 0; j < 4; ++j)
    f.i[j] = (int)pkbf(pp[2 * j] * sc, pp[2 * j + 1] * sc);
  return f;
}
} // namespace

#define MFMA(a, b, c) __builtin_amdgcn_mfma_f32_16x16x32_bf16(a, b, c, 0, 0, 0)
// LDS-only barrier: do NOT drain vmcnt (global h-stream stays in flight)
#define BAR() do { \
  asm volatile("s_waitcnt lgkmcnt(0)" ::: "memory"); \
  __builtin_amdgcn_s_barrier(); \
} while (0)

// ---------------------------------------------------------------------------
// Kernel 1: GRU-D recurrence. 64 blocks x 8 waves, one LDS-only barrier/step.
// MFMA operands swapped (weights=A, state=B): D = [unit, batch] so each lane
// owns 4 consecutive units of one batch row -> 8B LDS write + 8B global store.
// hws layout: per (chain,t) a 4KB tile [batch(16)][unit(128)] bf16.
// ---------------------------------------------------------------------------
__global__ __launch_bounds__(512, 2)
void grud_rnn(const float* __restrict__ x, const float* __restrict__ x_mean,
              const float* __restrict__ dxw, const float* __restrict__ dxb,
              const float* __restrict__ dhw, const float* __restrict__ dhb,
              const float* __restrict__ w_ih, const float* __restrict__ w_hh,
              const float* __restrict__ b_ih, const float* __restrict__ b_hh,
              char* __restrict__ hws, float* __restrict__ hstate,
              float* __restrict__ runst, float* __restrict__ xlst,
              int t0, int Tc)
{
  __shared__ __align__(16) float          xw[2][16][17];   // x rows, 17-pad
  __shared__ __align__(16) unsigned short gin[2][16][40];  // interleaved x̂/m + bias
  __shared__ __align__(16) unsigned short hdL[2][2048];    // [b][u] cell-swizzled

  const int tid = threadIdx.x, lane = tid & 63, wv = tid >> 6;
  const int lr = lane & 15, lg = lane >> 4;
  const int b0 = blockIdx.x * 16;
  const int uidx = wv * 16 + lr;     // weight-row index (A operand)
  const int uu0  = wv * 16 + 4 * lg; // this lane's first owned unit (D rows)

  // ---- weight fragments (A operand; r,z scaled -log2e; n scaled +2log2e) ----
  FRAG bhh[3][4], bgi[3];
  #pragma unroll
  for (int g = 0; g < 3; ++g) {
    const float sc = (g < 2) ? -L2E : 2.f * L2E;
    const int grow = g * 128 + uidx;
    const float* wrow = w_hh + (size_t)grow * NH;
    #pragma unroll
    for (int s = 0; s < 4; ++s) bhh[g][s] = pk8(wrow + 32 * s + 8 * lg, sc);
    FRAG f; f.i = i32x4{0, 0, 0, 0};
    if (lg < 2) {
      unsigned e[8];
      #pragma unroll
      for (int j = 0; j < 8; ++j) {
        const int c = 8 * lg + j; float v = 0.f;
        if (c < 12) {
          const int ch = c >> 1;
          v = ((c & 1) ? w_ih[(size_t)grow * 12 + 6 + ch]
                       : w_ih[(size_t)grow * 12 + ch]) * sc;
        } else if (c == 12) {
          v = ((g < 2) ? (b_ih[grow] + b_hh[grow]) : b_ih[grow]) * sc;
        }
        e[j] = bfb(v);
      }
      f.i[0] = (int)(e[0] | (e[1] << 16)); f.i[1] = (int)(e[2] | (e[3] << 16));
      f.i[2] = (int)(e[4] | (e[5] << 16)); f.i[3] = (int)(e[6] | (e[7] << 16));
    }
    bgi[g] = f;
  }
  // per-unit vectors for this lane's 4 owned units
  f32x4 dhwV, dhbV, bhnV;
  #pragma unroll
  for (int r = 0; r < 4; ++r) {
    dhwV[r] = -L2E * dhw[uu0 + r];
    dhbV[r] = -L2E * dhb[uu0 + r];
    bhnV[r] = b_hh[256 + uu0 + r] * (2.f * L2E);
  }

  // ---- x̂ lanes: waves 0-3, lanes 0..23 ----
  const int  item = wv * 24 + lane;
  const bool xl = (wv < 4) && (lane < 24);
  const int  xrow = item / 6, xch = item - 6 * (item / 6);
  float dxwS = 0.f, dxbS = 0.f, xm_l = 0.f, run = 0.f, xlast = 0.f;
  if (xl) {
    dxwS = -L2E * dxw[xch]; dxbS = -L2E * dxb[xch]; xm_l = x_mean[xch];
    if (t0 > 0) { run = runst[(b0 + xrow) * 6 + xch]; xlast = xlst[(b0 + xrow) * 6 + xch]; }
  }

  // ---- stagers: waves 4-7 ----
  const bool sl = (tid >= 256) && (tid < 464);
  const int sid = tid - 256;
  const int rrow = sid / 13, rcc = sid - 13 * (sid / 13);
  const float* xbase = x + (size_t)(b0 + rrow) * (NT * 13) + rcc;

  // ---- h state: lane = (batch lr, units uu0..uu0+3) ----
  f32x4 hn = {0.f, 0.f, 0.f, 0.f};
  if (t0 > 0) hn = *(const f32x4*)&hstate[(size_t)(b0 + lr) * NH + uu0];

  // ---- constant LDS byte offsets ----
  const int wOff = lr * 256 + ((((2 * wv + (lg >> 1))) ^ (lr & 7)) << 4) + (lg & 1) * 8;
  int rOff[4];
  #pragma unroll
  for (int s = 0; s < 4; ++s) rOff[s] = lr * 256 + (((4 * s + lg) ^ (lr & 7)) << 4);

  // ---- gin tails (cols 12..39: bias col 12 = 1.0, rest 0; both buffers) ----
  for (int i = tid; i < 2 * 16 * 28; i += 512) {
    const int buf = i / 448, rem = i - 448 * buf;
    const int row = rem / 28, c = 12 + rem - 28 * (rem / 28);
    gin[buf][row][c] = (c == 12) ? (unsigned short)0x3F80 : (unsigned short)0;
  }

  // ---- prologue ----
  const int cb0 = t0 & 1;
  if (sl) {
    xw[cb0][rrow][rcc]     = xbase[(size_t)t0 * 13];
    const int t1 = (t0 + 1 < NT) ? t0 + 1 : NT - 1;
    xw[cb0 ^ 1][rrow][rcc] = xbase[(size_t)t1 * 13];
  }
  __syncthreads();

  f32x4 hd;
  {
    const float dt0 = xw[cb0][lr][12];
    #pragma unroll
    for (int r = 0; r < 4; ++r)
      hd[r] = ex2(fminf(dt0 * dhwV[r] + dhbV[r], 0.f)) * hn[r];
    *(unsigned long long*)((char*)hdL + cb0 * 4096 + wOff) = pk4(hd);
  }
  if (xl) {
    const float xv = xw[cb0][xrow][xch], mt = xw[cb0][xrow][6 + xch];
    const float dtv = xw[cb0][xrow][12];
    const bool obs = mt > 0.5f;
    run = obs ? 0.f : run + dtv;
    const float gx = ex2(fminf(run * dxwS + dxbS, 0.f));
    xlast = obs ? xv : xlast;
    const float xh = mt * xv + (1.f - mt) * (gx * xlast + (1.f - gx) * xm_l);
    ((unsigned*)&gin[cb0][xrow][0])[xch] = pkbf(xh, mt);
  }
  float xr2 = 0.f;
  if (sl) { const int t2 = (t0 + 2 < NT) ? t0 + 2 : NT - 1; xr2 = xbase[(size_t)t2 * 13]; }
  BAR();

  char* hwp = hws + (((size_t)blockIdx.x * Tc) << 12) + wv * 32 + lg * 8 + lr * 256;
  const f32x4 z4 = {0.f, 0.f, 0.f, 0.f};
  const int tend = t0 + Tc;

  #pragma unroll 1
  for (int t = t0; t < tend; ++t) {
    const int p = t & 1, q = p ^ 1;

    // ---- reads (buffers of parity p; dt of t+1 from xw[q]) ----
    FRAG ag; ag.i = *(const i32x4*)&gin[p][lr][8 * lg];
    FRAG ah[4];
    #pragma unroll
    for (int s = 0; s < 4; ++s)
      ah[s].i = *(const i32x4*)((const char*)hdL + p * 4096 + rOff[s]);
    const float dtn = xw[q][lr][12];

    // ---- stage x[t+2] -> xw[p]; prefetch x[t+3] ----
    if (sl) {
      xw[p][rrow][rcc] = xr2;
      xr2 = xbase[(size_t)((t + 3 < NT) ? t + 3 : NT - 1) * 13];
    }

    // ---- MFMAs (weights = A, state = B): D = [unit, batch] ----
    f32x4 accr = MFMA(bgi[0].b, ag.b, z4);
    f32x4 accz = MFMA(bgi[1].b, ag.b, z4);
    f32x4 ani  = MFMA(bgi[2].b, ag.b, z4);
    f32x4 anh  = z4;
    #pragma unroll
    for (int s = 0; s < 4; ++s) {
      accr = MFMA(bhh[0][s].b, ah[s].b, accr);
      accz = MFMA(bhh[1][s].b, ah[s].b, accz);
      anh  = MFMA(bhh[2][s].b, ah[s].b, anh);
    }

    // ---- gate tail ----
    f32x4 hb = anh + bhnV;
    #pragma unroll
    for (int r = 0; r < 4; ++r) {
      const float rr = rcp_(1.f + ex2(accr[r]));
      const float zz = rcp_(1.f + ex2(accz[r]));
      const float na = ani[r] + rr * hb[r];
      const float nn = 1.f - 2.f * rcp_(1.f + ex2(na));
      hn[r] = nn + zz * (hd[r] - nn);
    }

    // ---- stream h_t (8B/lane, never drained at barrier) ----
    *(unsigned long long*)hwp = pk4(hn);
    hwp += 4096;

    // ---- decay for t+1 + LDS write ----
    #pragma unroll
    for (int r = 0; r < 4; ++r)
      hd[r] = ex2(fminf(dtn * dhwV[r] + dhbV[r], 0.f)) * hn[r];
    *(unsigned long long*)((char*)hdL + q * 4096 + wOff) = pk4(hd);

    // ---- x̂ for t+1 ----
    if (xl && t + 1 < tend) {
      const float xv = xw[q][xrow][xch], mt = xw[q][xrow][6 + xch];
      const float dtv = xw[q][xrow][12];
      const bool obs = mt > 0.5f;
      run = obs ? 0.f : run + dtv;
      const float gx = ex2(fminf(run * dxwS + dxbS, 0.f));
      xlast = obs ? xv : xlast;
      const float xh = mt * xv + (1.f - mt) * (gx * xlast + (1.f - gx) * xm_l);
      ((unsigned*)&gin[q][xrow][0])[xch] = pkbf(xh, mt);
    }
    BAR();
  }

  // ---- carry state ----
  *(f32x4*)&hstate[(size_t)(b0 + lr) * NH + uu0] = hn;
  if (xl) { runst[(b0 + xrow) * 6 + xch] = run; xlst[(b0 + xrow) * 6 + xch] = xlast; }
}

// ---------------------------------------------------------------------------
// Kernel 2: heads, full-chip. Block = 256 thr (4 waves) = (chain, 4 t-steps).
// Stages 4x 4KB h-tiles [b][u] with cell swizzle; L1 then L2 per round-2.
// ---------------------------------------------------------------------------
__global__ __launch_bounds__(256, 2)
void grud_head(const char* __restrict__ hws,
               const float* __restrict__ w1, const float* __restrict__ b1,
               const float* __restrict__ w2, const float* __restrict__ b2,
               const float* __restrict__ wu1, const float* __restrict__ bu1,
               const float* __restrict__ wu2, const float* __restrict__ bu2,
               float* __restrict__ out, int t0, int Tc)
{
  __shared__ __align__(16) unsigned short hsL[4][2048];  // 4 t-tiles [b][u] swz
  __shared__ __align__(16) unsigned short y1s[64][128];  // [k*16+b][y1u] swz
  __shared__ __align__(16) unsigned short u1s[64][64];   // [k*16+b][u1u] swz

  const int tid = threadIdx.x, lane = tid & 63, wv = tid >> 6;
  const int lr = lane & 15, lg = lane >> 4;
  const int c = blockIdx.x & 63, gq = blockIdx.x >> 6;

  // stage h tiles (cell-swizzled)
  const char* src = hws + (((size_t)c * Tc + gq * 4) << 12);
  #pragma unroll
  for (int k2 = 0; k2 < 4; ++k2) {
    const int o = tid * 16, row = o >> 8, cell = (o >> 4) & 15;
    uint4 v = *(const uint4*)(src + k2 * 4096 + o);
    *(uint4*)((char*)hsL + k2 * 4096 + row * 256 + ((cell ^ (row & 7)) << 4)) = v;
  }

  // weight fragments (B operands, k = 32s+8lg+j)
  FRAG bw1a[4], bw1b[4], bq1[4], bw2[4], bq2[2];
  const int ct0 = 2 * wv, ct1 = 2 * wv + 1;
  #pragma unroll
  for (int s = 0; s < 4; ++s) {
    bw1a[s] = pk8(w1 + (size_t)(ct0 * 16 + lr) * 128 + 32 * s + 8 * lg, 1.f);
    bw1b[s] = pk8(w1 + (size_t)(ct1 * 16 + lr) * 128 + 32 * s + 8 * lg, 1.f);
    bq1[s]  = pk8(wu1 + (size_t)(wv * 16 + lr) * 128 + 32 * s + 8 * lg, 1.f);
    if (lr < 6) bw2[s] = pk8(w2 + (size_t)lr * 128 + 32 * s + 8 * lg, 1.f);
    else        bw2[s].i = i32x4{0, 0, 0, 0};
    if (s < 2) {
      if (lr < 6) bq2[s] = pk8(wu2 + (size_t)lr * 64 + 32 * s + 8 * lg, 1.f);
      else        bq2[s].i = i32x4{0, 0, 0, 0};
    }
  }
  const float b1a = b1[ct0 * 16 + lr], b1b = b1[ct1 * 16 + lr];
  const float bu1l = bu1[wv * 16 + lr];
  const float b2l = (lr < 6) ? b2[lr] : 0.f, bu2l = (lr < 6) ? bu2[lr] : 0.f;
  const f32x4 z4 = {0.f, 0.f, 0.f, 0.f};
  __syncthreads();

  // ---- layer 1: 4 t-tiles ----
  const int cy0 = ct0 * 16 + lr, cy1 = ct1 * 16 + lr, cu = wv * 16 + lr;
  #pragma unroll
  for (int k = 0; k < 4; ++k) {
    FRAG A[4];
    #pragma unroll
    for (int s = 0; s < 4; ++s)
      A[s].i = *(const i32x4*)((const char*)hsL + k * 4096 + lr * 256 +
                               (((4 * s + lg) ^ (lr & 7)) << 4));
    f32x4 aa = z4, ab = z4, au = z4;
    #pragma unroll
    for (int s = 0; s < 4; ++s) {
      aa = MFMA(A[s].b, bw1a[s].b, aa);
      ab = MFMA(A[s].b, bw1b[s].b, ab);
      au = MFMA(A[s].b, bq1[s].b, au);
    }
    #pragma unroll
    for (int r = 0; r < 4; ++r) {
      const int m = k * 16 + 4 * lg + r;
      *(unsigned short*)((char*)y1s + m * 256 + (((cy0 >> 3) ^ (m & 7)) << 4) +
                         (cy0 & 7) * 2) = bfb(fmaxf(aa[r] + b1a, 0.f));
      *(unsigned short*)((char*)y1s + m * 256 + (((cy1 >> 3) ^ (m & 7)) << 4) +
                         (cy1 & 7) * 2) = bfb(fmaxf(ab[r] + b1b, 0.f));
      *(unsigned short*)((char*)u1s + m * 128 + (((cu >> 3) ^ (m & 7)) << 4) +
                         (cu & 7) * 2) = bfb(fmaxf(au[r] + bu1l, 0.f));
    }
  }
  __syncthreads();

  // ---- layer 2: wave wv finishes t-tile wv ----
  const int mrow = wv * 16 + lr;
  FRAG Y[4], U[2];
  #pragma unroll
  for (int s = 0; s < 4; ++s)
    Y[s].i = *(const i32x4*)((const char*)y1s + mrow * 256 +
                             (((4 * s + lg) ^ (lr & 7)) << 4));
  #pragma unroll
  for (int s = 0; s < 2; ++s)
    U[s].i = *(const i32x4*)((const char*)u1s + mrow * 128 +
                             (((4 * s + lg) ^ (lr & 7)) << 4));
  f32x4 ap = z4, aq = z4;
  #pragma unroll
  for (int s = 0; s < 4; ++s) ap = MFMA(Y[s].b, bw2[s].b, ap);
  #pragma unroll
  for (int s = 0; s < 2; ++s) aq = MFMA(U[s].b, bq2[s].b, aq);

  if (lr < 6) {
    const int t = t0 + gq * 4 + wv;
    #pragma unroll
    for (int r = 0; r < 4; ++r) {
      const int b = c * 16 + 4 * lg + r;
      const size_t o = ((size_t)b * NT + t) * 6 + lr;
      out[o] = ap[r] + b2l;
      const float xa = aq[r] + bu2l;
      const float sp = fmaxf(xa, 0.f) + 0.6931471805599453f *
          __builtin_amdgcn_logf(1.f + ex2(-fabsf(xa) * L2E));
      out[(size_t)NB * NT * 6 + o] = sp;
    }
  }
}

extern "C" void kernel_launch(void* const* d_in, const int* in_sizes, int n_in,
                              void* d_out, int out_size, void* d_ws, size_t ws_size,
                              hipStream_t stream) {
  (void)in_sizes; (void)n_in; (void)out_size;
  const float* p[18];
  for (int i = 0; i < 18; ++i) p[i] = (const float*)d_in[i];

  const size_t STATE = (size_t)1024 * 128 * 4 + 2 * (size_t)1024 * 6 * 4;
  int Tc = 1024;
  while (Tc > 16 && (((size_t)Tc << 18) + STATE) > ws_size) Tc >>= 1;

  char* hws = (char*)d_ws;
  float* hstate = (float*)(hws + ((size_t)Tc << 18));
  float* runst = hstate + 1024 * 128;
  float* xlst = runst + 1024 * 6;

  for (int t0 = 0; t0 < NT; t0 += Tc) {
    hipLaunchKernelGGL(grud_rnn, dim3(64), dim3(512), 0, stream,
                       p[0], p[1], p[2], p[3], p[4], p[5], p[6], p[7], p[8], p[9],
                       hws, hstate, runst, xlst, t0, Tc);
    hipLaunchKernelGGL(grud_head, dim3(64 * (Tc / 4)), dim3(256), 0, stream,
                       hws, p[10], p[11], p[12], p[13], p[14], p[15], p[16], p[17],
                       (float*)d_out, t0, Tc);
  }
}